// Round 7
// baseline (1487.921 us; speedup 1.0000x reference)
//
#include <hip/hip_runtime.h>
#include <hip/hip_bf16.h>

// R7: stop gating the 4-way split on host-side estimators (R5: occupancy API
// on the bf16 twin; R6: localSizeBytes poisoned by the noinline call frame's
// ABI stack -- both vetoed spuriously; runtime counters show zero actual
// spill traffic). hipLaunchCooperativeKernel itself validates co-residency
// and errors WITHOUT launching if the grid can't fit -- that is the ground
// truth. Launch ladder: <4,2> natural-alloc (cap 256, allocator picks 128)
// -> <4,4> forced cap 128 -> <2,1> proven 945us shape. Kernel code unchanged
// from R6 (fused phase + flag protocol, NPART=4 dep-graph re-audited).
#define BDIM 512
#define NBAT 128
#define SS   48
#define DD   8
#define HDIM 8
#define NL   8
#define NC   7
#define NWAV 8
#define PIX  (SS*SS)
#define RGN  (PIX*DD)            // one region: 18432 floats
#define GBAT (2*RGN)             // row+col regions per batch
#define BUFSZ ((size_t)NBAT*GBAT)      // one parity buffer (floats)
#define KVV  384
#define KVW  768
#define KVTOT (NWAV*KVW)
#define SMEMF_FLOATS (KVTOT + 264 + 784 + 8)
#define SMEMF_BYTES  (SMEMF_FLOATS*4)        // 28,800 B -> 2 blocks/CU LDS-wise
#define FLAGS_OFF ((size_t)2*BUFSZ)          // float offset of flags in d_ws

__device__ __forceinline__ float ldsel(const void* p, long i, bool bf) {
    return bf ? __bfloat162float(((const __hip_bfloat16*)p)[i])
              : ((const float*)p)[i];
}

__device__ __forceinline__ void flag_post(unsigned* f, unsigned v) {
    __threadfence();                                   // release: drain + L2 wb
    __hip_atomic_store(f, v, __ATOMIC_RELAXED, __HIP_MEMORY_SCOPE_AGENT);
}
__device__ __forceinline__ void flag_wait(unsigned* f, unsigned v) {
    while (__hip_atomic_load(f, __ATOMIC_RELAXED, __HIP_MEMORY_SCOPE_AGENT) < v)
        __builtin_amdgcn_s_sleep(1);
}

// Fused phase: input read straight from the exchange buffers, output straight
// to the other parity. "own" region matches this phase's orientation
// (self-written, index (prob*SS+tl): coalesced); "oth" is the opposite region
// (index (tl*SS+prob): 32B-scattered, L2-absorbed). FIRST=1: layer 0, read h0
// as-is from the own-layout copy (no relu, no add).
template <int NPROB, int FIRST>
__device__ __attribute__((noinline))
void attn_phase_f(const float4* __restrict__ gown, const float4* __restrict__ goth,
                  float4* __restrict__ gout, float* __restrict__ kvw,
                  const float* __restrict__ wb, int pbase, int wav, int lane, int tl)
{
    const float4* kv4 = reinterpret_cast<const float4*>(kvw);
    #pragma unroll 1
    for (int p = 0; p < NPROB/NWAV; ++p) {
        const int prob = pbase + wav + p*NWAV;
        const int aown = (prob*SS + tl)*2;

        float ht[DD];
        {
            const float4 o0 = gown[aown], o1 = gown[aown+1];
            if (FIRST) {
                ht[0]=o0.x; ht[1]=o0.y; ht[2]=o0.z; ht[3]=o0.w;
                ht[4]=o1.x; ht[5]=o1.y; ht[6]=o1.z; ht[7]=o1.w;
            } else {
                const int aoth = (tl*SS + prob)*2;
                const float4 t0 = goth[aoth], t1 = goth[aoth+1];
                ht[0]=fmaxf(0.f,o0.x+t0.x); ht[1]=fmaxf(0.f,o0.y+t0.y);
                ht[2]=fmaxf(0.f,o0.z+t0.z); ht[3]=fmaxf(0.f,o0.w+t0.w);
                ht[4]=fmaxf(0.f,o1.x+t1.x); ht[5]=fmaxf(0.f,o1.y+t1.y);
                ht[6]=fmaxf(0.f,o1.z+t1.z); ht[7]=fmaxf(0.f,o1.w+t1.w);
            }
        }

        // q/k/v projections; fold 0.5 (E^-0.5) * log2(e) into q for exp2.
        float q[HDIM];
        {
            float kk[HDIM], vv[HDIM];
            #pragma unroll
            for (int o = 0; o < HDIM; ++o) {
                float aq = 0.f, ak = 0.f, av = 0.f;
                #pragma unroll
                for (int d = 0; d < DD; ++d) {
                    aq += ht[d] * wb[o*8 + d];
                    ak += ht[d] * wb[64 + o*8 + d];
                    av += ht[d] * wb[128 + o*8 + d];
                }
                q[o] = aq * 0.72134752044f;  // 0.5 * log2(e)
                kk[o] = ak; vv[o] = av;
            }
            if (lane < SS) {   // lanes 48-63 would duplicate token 47: skip
                float4* kp = reinterpret_cast<float4*>(kvw + tl*8);
                kp[0] = make_float4(kk[0], kk[1], kk[2], kk[3]);
                kp[1] = make_float4(kk[4], kk[5], kk[6], kk[7]);
                float4* vp = reinterpret_cast<float4*>(kvw + KVV + tl*8);
                vp[0] = make_float4(vv[0], vv[1], vv[2], vv[3]);
                vp[1] = make_float4(vv[4], vv[5], vv[6], vv[7]);
            }
        }

        float ov[HDIM];
        #pragma unroll
        for (int hh = 0; hh < 2; ++hh) {
            float dt[SS];
            #pragma unroll
            for (int j2 = 0; j2 < SS; ++j2) {
                const float4 kk4 = kv4[j2*2 + hh];       // LDS same-addr broadcast
                float acc =  q[hh*4+0] * kk4.x;
                acc       += q[hh*4+1] * kk4.y;
                acc       += q[hh*4+2] * kk4.z;
                acc       += q[hh*4+3] * kk4.w;
                dt[j2] = acc;
            }
            // max tree (fmax exactly associative -> bitwise same as chain)
            float mt[24];
            #pragma unroll
            for (int t2 = 0; t2 < 24; ++t2) mt[t2] = fmaxf(dt[t2], dt[t2+24]);
            #pragma unroll
            for (int t2 = 0; t2 < 12; ++t2) mt[t2] = fmaxf(mt[t2], mt[t2+12]);
            #pragma unroll
            for (int t2 = 0; t2 < 6; ++t2)  mt[t2] = fmaxf(mt[t2], mt[t2+6]);
            #pragma unroll
            for (int t2 = 0; t2 < 3; ++t2)  mt[t2] = fmaxf(mt[t2], mt[t2+3]);
            const float m = fmaxf(fmaxf(mt[0], mt[1]), mt[2]);
            float s = 0.f;
            #pragma unroll
            for (int j2 = 0; j2 < SS; ++j2) {
                float pv = exp2f(dt[j2] - m);
                dt[j2] = pv; s += pv;
            }
            float o0 = 0.f, o1 = 0.f, o2 = 0.f, o3 = 0.f;
            #pragma unroll
            for (int j2 = 0; j2 < SS; ++j2) {
                const float4 vv4 = kv4[KVV/4 + j2*2 + hh];
                const float pv = dt[j2];
                o0 += pv * vv4.x;
                o1 += pv * vv4.y;
                o2 += pv * vv4.z;
                o3 += pv * vv4.w;
            }
            float rs = 1.f / s;
            ov[hh*4+0] = o0*rs; ov[hh*4+1] = o1*rs;
            ov[hh*4+2] = o2*rs; ov[hh*4+3] = o3*rs;
        }

        if (lane < SS) {
            float o8[DD];
            #pragma unroll
            for (int d = 0; d < DD; ++d) {
                float acc = wb[256 + d];
                #pragma unroll
                for (int o2 = 0; o2 < HDIM; ++o2) acc += ov[o2] * wb[192 + d*8 + o2];
                o8[d] = acc;
            }
            gout[aown]   = make_float4(o8[0], o8[1], o8[2], o8[3]);
            gout[aown+1] = make_float4(o8[4], o8[5], o8[6], o8[7]);
        }
    }
}

// NPART=4: 512 blocks (2 halves x 2 axes per batch). NPART=2: 256 blocks.
// MINW: __launch_bounds__ min-waves/EU (2 = cap 256 natural alloc; 4 = cap 128).
template <int NPART, int MINW>
__global__ void __launch_bounds__(BDIM, MINW)
axial_u(const void* xv, const void* enc_wv, const void* enc_bv,
        const void* pos_rowv, const void* pos_colv,
        const void* Wqv, const void* Wkv, const void* Wvv, const void* Wov,
        const void* bov, const void* cls_wv, const void* cls_bv,
        void* outv, void* wsv)
{
    // dtype sniff on x (wave-uniform): low bits of each dword are a plausible
    // bf16 exponent iff data is bf16-packed; random mantissa bits if fp32.
    const unsigned* xu = (const unsigned*)xv;
    int cnt = 0;
    #pragma unroll
    for (int t = 0; t < 32; ++t) {
        const unsigned w = xu[t];
        const int e = (w >> 7) & 0xff;
        cnt += (e > 100 && e < 150) ? 1 : 0;
    }
    const bool isbf = (cnt >= 20);

    float*    G     = (float*)wsv;
    unsigned* flags = (unsigned*)(G + FLAGS_OFF);

    extern __shared__ float smem[];
    float* kv = smem;              // per-wave k/v scratch [KVTOT]
    float* wb = kv + KVTOT;        // layer weights (own axis) [264]
    float* eb = wb + 264;          // enc params [784]
    float* cb = eb + 784;          // classifier logits [8]

    const int bid   = blockIdx.x;
    const int batch = bid & (NBAT-1);
    const int part  = bid >> 7;                         // 0..NPART-1
    const int axis  = (NPART == 4) ? (part >> 1) : part;
    const int pbase = (NPART == 4) ? ((part & 1) * (SS/2)) : 0;
    constexpr int NPROB = (NPART == 4) ? (SS/2) : SS;
    const int tid   = threadIdx.x;
    const int lane  = tid & 63;
    const int wav   = tid >> 6;
    const int tl    = lane < SS ? lane : SS-1;
    float* kvw = kv + wav*KVW;

    float* b0 = G + (size_t)batch*GBAT;                 // parity-0 buffer
    float* b1 = G + BUFSZ + (size_t)batch*GBAT;         // parity-1 buffer
    float4* row0 = (float4*)b0;  float4* col0 = (float4*)(b0 + RGN);
    float4* row1 = (float4*)b1;  float4* col1 = (float4*)(b1 + RGN);

    // stage encoder/pos params
    for (int f = tid; f < 784; f += BDIM) {
        float v;
        if (f < 8)        v = ldsel(enc_wv, f, isbf);
        else if (f < 16)  v = ldsel(enc_bv, f-8, isbf);
        else if (f < 400) v = ldsel(pos_rowv, f-16, isbf);
        else              v = ldsel(pos_colv, f-400, isbf);
        eb[f] = v;
    }
    __syncthreads();

    // encoder: h0 = relu(x*enc_w + enc_b) + pos_row[i] + pos_col[j].
    // Every sibling writes the FULL image in BOTH layouts (identical values ->
    // benign race; own copy guarantees own-visibility, so no startup gate).
    for (int p = tid; p < PIX; p += BDIM) {
        const int i = p / SS, j = p % SS;
        const float xv2 = ldsel(xv, (long)batch*PIX + p, isbf);
        float hv[DD];
        #pragma unroll
        for (int d = 0; d < DD; ++d)
            hv[d] = fmaxf(0.f, xv2*eb[d] + eb[8+d]) + eb[16 + i*8 + d] + eb[400 + j*8 + d];
        const float4 a = make_float4(hv[0], hv[1], hv[2], hv[3]);
        const float4 b = make_float4(hv[4], hv[5], hv[6], hv[7]);
        col0[p*2] = a;              col0[p*2+1] = b;            // [i][j][d]
        row0[(j*SS+i)*2] = a;       row0[(j*SS+i)*2+1] = b;     // [j][i][d]
    }

    // Layer l: reads parity l&1, writes parity (l+1)&1. WV(l)=l+1 posted after
    // the phase. Gate before layer l>0: opposite-axis siblings' WV(l-1) (own
    // region is self-written; double-buffer makes WV imply read-safety).
    #pragma unroll 1
    for (int l = 0; l < NL; ++l) {
        __syncthreads();                     // prior phase wb reads / encoder done
        if (tid == 0 && l > 0) {
            if (NPART == 4) {
                const int ob = axis ? 0 : 2;
                flag_wait(&flags[batch + ob*NBAT],     (unsigned)l);
                flag_wait(&flags[batch + (ob+1)*NBAT], (unsigned)l);
            } else {
                flag_wait(&flags[batch + (1-axis)*NBAT], (unsigned)l);
            }
            __threadfence();                 // acquire: invalidate stale caches
        }
        const int la = l*2 + axis;
        for (int f = tid; f < 264; f += BDIM) {
            float v;
            if (f < 64)       v = ldsel(Wqv, la*64 + f, isbf);
            else if (f < 128) v = ldsel(Wkv, la*64 + f-64, isbf);
            else if (f < 192) v = ldsel(Wvv, la*64 + f-128, isbf);
            else if (f < 256) v = ldsel(Wov, la*64 + f-192, isbf);
            else              v = ldsel(bov, la*8 + f-256, isbf);
            wb[f] = v;
        }
        __syncthreads();                     // gate released + wb visible

        const int par = l & 1;
        float4* rin  = par ? row1 : row0;  float4* cin  = par ? col1 : col0;
        float4* rout = par ? row0 : row1;  float4* cout = par ? col0 : col1;
        const float4* own = axis ? (const float4*)cin : (const float4*)rin;
        const float4* oth = axis ? (const float4*)rin : (const float4*)cin;
        float4* gout = axis ? cout : rout;

        if (l == 0) attn_phase_f<NPROB,1>(own, oth, gout, kvw, wb, pbase, wav, lane, tl);
        else        attn_phase_f<NPROB,0>(own, oth, gout, kvw, wb, pbase, wav, lane, tl);
        __syncthreads();                     // drains each wave's global stores

        if (tid == 0) flag_post(&flags[bid], (unsigned)(l + 1));
    }

    if (part != 0) return;

    // classifier (part 0 of each batch): final h lives in parity 0 (NL even).
    if (tid == 0) {
        #pragma unroll
        for (int qp = 1; qp < NPART; ++qp)
            flag_wait(&flags[batch + qp*NBAT], (unsigned)NL);
        __threadfence();
    }
    if (tid < NC) cb[tid] = ldsel(cls_bv, tid, isbf);
    __syncthreads();

    float pacc[NC] = {0.f,0.f,0.f,0.f,0.f,0.f,0.f};
    const float* cwf = (const float*)cls_wv;
    const __hip_bfloat16* cwb = (const __hip_bfloat16*)cls_wv;
    for (int p = tid; p < PIX; p += BDIM) {
        const int i = p / SS, j = p % SS;
        const float4 c0 = col0[p*2], c1 = col0[p*2+1];
        const float4 r0 = row0[(j*SS+i)*2], r1 = row0[(j*SS+i)*2+1];
        float mv =            fmaxf(0.f, c0.x + r0.x);
        mv = fmaxf(mv,        fmaxf(0.f, c0.y + r0.y));
        mv = fmaxf(mv,        fmaxf(0.f, c0.z + r0.z));
        mv = fmaxf(mv,        fmaxf(0.f, c0.w + r0.w));
        mv = fmaxf(mv,        fmaxf(0.f, c1.x + r1.x));
        mv = fmaxf(mv,        fmaxf(0.f, c1.y + r1.y));
        mv = fmaxf(mv,        fmaxf(0.f, c1.z + r1.z));
        mv = fmaxf(mv,        fmaxf(0.f, c1.w + r1.w));
        if (isbf) {
            #pragma unroll
            for (int c = 0; c < NC; ++c) pacc[c] += mv * __bfloat162float(cwb[c*PIX + p]);
        } else {
            #pragma unroll
            for (int c = 0; c < NC; ++c) pacc[c] += mv * cwf[c*PIX + p];
        }
    }
    #pragma unroll
    for (int c = 0; c < NC; ++c) {
        #pragma unroll
        for (int off = 32; off > 0; off >>= 1) pacc[c] += __shfl_down(pacc[c], off, 64);
    }
    if (lane == 0) {
        #pragma unroll
        for (int c = 0; c < NC; ++c) atomicAdd(&cb[c], pacc[c]);
    }
    __syncthreads();

    if (tid < NC) {
        float m = cb[0];
        #pragma unroll
        for (int c = 1; c < NC; ++c) m = fmaxf(m, cb[c]);
        float s = 0.f;
        #pragma unroll
        for (int c = 0; c < NC; ++c) s += exp2f((cb[c]-m) * 1.44269504089f);
        const float e = exp2f((cb[tid]-m) * 1.44269504089f);
        const float r = e / s;
        if (isbf) ((__hip_bfloat16*)outv)[batch*NC + tid] = __float2bfloat16(r);
        else      ((float*)outv)[batch*NC + tid] = r;
    }
}

extern "C" void kernel_launch(void* const* d_in, const int* in_sizes, int n_in,
                              void* d_out, int out_size, void* d_ws, size_t ws_size,
                              hipStream_t stream) {
    (void)in_sizes; (void)n_in; (void)ws_size; (void)out_size;
    hipFuncSetAttribute(reinterpret_cast<const void*>(&axial_u<4,2>),
                        hipFuncAttributeMaxDynamicSharedMemorySize, SMEMF_BYTES);
    hipFuncSetAttribute(reinterpret_cast<const void*>(&axial_u<4,4>),
                        hipFuncAttributeMaxDynamicSharedMemorySize, SMEMF_BYTES);
    hipFuncSetAttribute(reinterpret_cast<const void*>(&axial_u<2,1>),
                        hipFuncAttributeMaxDynamicSharedMemorySize, SMEMF_BYTES);

    // zero epoch flags (stream-ordered, graph-capture-safe)
    hipMemsetAsync((char*)d_ws + FLAGS_OFF*4, 0, 512*sizeof(unsigned), stream);

    void* ins[12];
    for (int i = 0; i < 12; ++i) ins[i] = d_in[i];
    void* args[14];
    for (int i = 0; i < 12; ++i) args[i] = &ins[i];
    args[12] = &d_out;
    args[13] = &d_ws;     // needs 2*BUFSZ*4 + 512*4 ~= 37.75 MB (present since R5)

    // Ground-truth gating: the cooperative launch itself validates that the
    // grid can be fully co-resident and returns an error WITHOUT launching
    // otherwise. Ladder: 4-way natural-alloc -> 4-way forced-cap -> 2-way.
    hipError_t err = hipLaunchCooperativeKernel(
        reinterpret_cast<const void*>(&axial_u<4,2>),
        dim3(4*NBAT), dim3(BDIM), args, (unsigned)SMEMF_BYTES, stream);
    if (err != hipSuccess) {
        err = hipLaunchCooperativeKernel(
            reinterpret_cast<const void*>(&axial_u<4,4>),
            dim3(4*NBAT), dim3(BDIM), args, (unsigned)SMEMF_BYTES, stream);
    }
    if (err != hipSuccess) {
        hipLaunchCooperativeKernel(
            reinterpret_cast<const void*>(&axial_u<2,1>),
            dim3(2*NBAT), dim3(BDIM), args, (unsigned)SMEMF_BYTES, stream);
    }
}